// Round 6
// baseline (105.797 us; speedup 1.0000x reference)
//
#include <hip/hip_runtime.h>

#define SEQ 2048
#define BSZ 2
#define NHEAD 16
#define HDIM 64
#define QBLK 64
#define KVBLK 64
#define NKV (SEQ / KVBLK)   // 32
#define NQT (SEQ / QBLK)    // 32
#define KSTR 88             // K tile LDS stride (bf16 elems)
#define VSTR 72             // Vt/Zt LDS stride
#define ROWSTRIDE (BSZ * NHEAD * HDIM)

typedef __bf16 bf16x8 __attribute__((ext_vector_type(8)));
typedef __bf16 bf16x4 __attribute__((ext_vector_type(4)));
typedef __bf16 bf16x2 __attribute__((ext_vector_type(2)));
typedef float f32x4 __attribute__((ext_vector_type(4)));
typedef unsigned int uint;
typedef uint uint4v __attribute__((ext_vector_type(4)));

// XOR swizzle on the column index for transposed tiles (Vt, Zt).
__device__ __forceinline__ int vswz(int row, int col) {
  return row * VSTR + (col ^ (((row >> 2) & 7) << 3));
}

__global__ __launch_bounds__(256)
void ntk_attn(const float* __restrict__ Qg, const float* __restrict__ Kg,
              const float* __restrict__ Vg, const float* __restrict__ PKg,
              const float* __restrict__ PKVg, float* __restrict__ Og) {
  __shared__ __bf16 Ks[KVBLK * KSTR];   // K tile [kv][d]
  __shared__ __bf16 Vts[HDIM * VSTR];   // V transposed, swizzled
  __shared__ __bf16 Zts[HDIM * VSTR];   // Z transposed, swizzled
  __shared__ float kks[HDIM];
  __shared__ float red[4][16];

  const int tid = threadIdx.x;
  const int w = tid >> 6, l = tid & 63, lr = l & 15, lg = l >> 4;
  const int bh = blockIdx.y, h = bh & (NHEAD - 1);
  const int bx = NQT - 1 - blockIdx.x;   // longest blocks dispatch first
  const int q0 = bx * QBLK;
  const int headoff = bh * HDIM;

  // ---- Q fragments (pre-scaled by 1/sqrt(d)) + phi(Q); m'=0 softmax ref ----
  bf16x8 aq[2], pq[2];
  {
    const float* qp = Qg + (size_t)(q0 + w * 16 + lr) * ROWSTRIDE + headoff + lg * 8;
#pragma unroll
    for (int c = 0; c < 2; ++c) {
      const float4 x0 = *(const float4*)(qp + 32 * c);
      const float4 x1 = *(const float4*)(qp + 32 * c + 4);
      const float f[8] = {x0.x, x0.y, x0.z, x0.w, x1.x, x1.y, x1.z, x1.w};
#pragma unroll
      for (int i = 0; i < 8; ++i) {
        aq[c][i] = (__bf16)(f[i] * 0.125f);
        const float xs = f[i] * 0.3535533905932738f;
        pq[c][i] = (__bf16)(xs > 0.f ? xs + 1.f : __expf(xs));
      }
    }
  }

  // ---- stage Zt (transposed, swizzled) and |kk| ----
  {
#pragma unroll
    for (int it = 0; it < 4; ++it) {
      const int din = (tid >> 4) + 16 * it;
      const int c4 = (tid & 15) * 4;
      const float4 z = *(const float4*)(PKVg + (size_t)h * HDIM * HDIM +
                                        (size_t)din * HDIM + c4);
      Zts[vswz(c4 + 0, din)] = (__bf16)z.x;
      Zts[vswz(c4 + 1, din)] = (__bf16)z.y;
      Zts[vswz(c4 + 2, din)] = (__bf16)z.z;
      Zts[vswz(c4 + 3, din)] = (__bf16)z.w;
    }
    if (tid < HDIM) kks[tid] = fabsf(PKg[h * HDIM + tid]);
  }

  const f32x4 z4 = {0.f, 0.f, 0.f, 0.f};
  f32x4 oacc[4] = {z4, z4, z4, z4};
  float lsum = 0.f;                       // per-lane, q = lr, its k-slice
  const int qa = q0 + w * 16 + lr;        // absolute q row for this lane (swapped)

  // ---- register-staged prefetch ----
  const int stg_r = tid >> 4;
  const int stg_c4 = (tid & 15) * 4;
  float4 kreg[4], vreg[4];
  auto issue_k = [&](int kb) {
#pragma unroll
    for (int it = 0; it < 4; ++it)
      kreg[it] = *(const float4*)(Kg + (size_t)(kb * KVBLK + stg_r + 16 * it) * ROWSTRIDE +
                                  headoff + stg_c4);
  };
  auto issue_v = [&](int kb) {
#pragma unroll
    for (int it = 0; it < 4; ++it)
      vreg[it] = *(const float4*)(Vg + (size_t)(kb * KVBLK + stg_r + 16 * it) * ROWSTRIDE +
                                  headoff + stg_c4);
  };
  auto write_k = [&]() {
#pragma unroll
    for (int it = 0; it < 4; ++it) {
      bf16x4 p = {(__bf16)kreg[it].x, (__bf16)kreg[it].y,
                  (__bf16)kreg[it].z, (__bf16)kreg[it].w};
      *(bf16x4*)&Ks[(stg_r + 16 * it) * KSTR + stg_c4] = p;
    }
  };
  auto write_v = [&]() {
#pragma unroll
    for (int it = 0; it < 4; ++it) {
      const int r = stg_r + 16 * it;
      Vts[vswz(stg_c4 + 0, r)] = (__bf16)vreg[it].x;
      Vts[vswz(stg_c4 + 1, r)] = (__bf16)vreg[it].y;
      Vts[vswz(stg_c4 + 2, r)] = (__bf16)vreg[it].z;
      Vts[vswz(stg_c4 + 3, r)] = (__bf16)vreg[it].w;
    }
  };

  // ---- prologue: tile 0 resident, tile 1 in flight ----
  issue_k(0); issue_v(0);
  write_k(); write_v();
  if (bx >= 1) { issue_k(1); issue_v(1); }
  __syncthreads();

  // shuffle source lanes for P redistribution (constant per lane)
  const int src1 = lr + 32 * (lg & 1);
  const int src2 = src1 + 16;
  const bool useO = (lg >= 2);

  // ==== main loop: causal tiles, swapped QK^T, P stays in registers ====
  for (int kb = 0; kb <= bx; ++kb) {
    const int kv0 = kb * KVBLK;

    // S^T = K (Q/sqrt(d))^T : lane holds S[q=lr][k=kv0+16nj+4lg+r]
    f32x4 s4[4];
    __builtin_amdgcn_s_setprio(1);
#pragma unroll
    for (int nj = 0; nj < 4; ++nj) {
      f32x4 acc = z4;
#pragma unroll
      for (int c = 0; c < 2; ++c) {
        const bf16x8 bk = *(const bf16x8*)&Ks[(nj * 16 + lr) * KSTR + 32 * c + lg * 8];
        acc = __builtin_amdgcn_mfma_f32_16x16x32_bf16(bk, aq[c], acc, 0, 0, 0);
      }
      s4[nj] = acc;
    }
    __builtin_amdgcn_s_setprio(0);

    // P = exp(S) (mask only the diagonal tile), packed to bf16 dwords
    uint dw[4][2];
    if (kb == bx) {
#pragma unroll
      for (int nj = 0; nj < 4; ++nj) {
        float p[4];
#pragma unroll
        for (int r = 0; r < 4; ++r) {
          const int kabs = kv0 + 16 * nj + 4 * lg + r;
          p[r] = (kabs <= qa) ? __expf(s4[nj][r]) : 0.f;
        }
        lsum += (p[0] + p[1]) + (p[2] + p[3]);
        bf16x2 t0 = {(__bf16)p[0], (__bf16)p[1]};
        bf16x2 t1 = {(__bf16)p[2], (__bf16)p[3]};
        dw[nj][0] = __builtin_bit_cast(uint, t0);
        dw[nj][1] = __builtin_bit_cast(uint, t1);
      }
    } else {
#pragma unroll
      for (int nj = 0; nj < 4; ++nj) {
        float p[4];
#pragma unroll
        for (int r = 0; r < 4; ++r) p[r] = __expf(s4[nj][r]);
        lsum += (p[0] + p[1]) + (p[2] + p[3]);
        bf16x2 t0 = {(__bf16)p[0], (__bf16)p[1]};
        bf16x2 t1 = {(__bf16)p[2], (__bf16)p[3]};
        dw[nj][0] = __builtin_bit_cast(uint, t0);
        dw[nj][1] = __builtin_bit_cast(uint, t1);
      }
    }

    // redistribute P to A-frag layout (8 shfl + 4 sel per 32-k chunk) and PV
#pragma unroll
    for (int c = 0; c < 2; ++c) {
      const uint a0 = __shfl((int)dw[2 * c][0], src1);
      const uint b0 = __shfl((int)dw[2 * c + 1][0], src1);
      const uint a1 = __shfl((int)dw[2 * c][1], src1);
      const uint b1 = __shfl((int)dw[2 * c + 1][1], src1);
      const uint a2 = __shfl((int)dw[2 * c][0], src2);
      const uint b2 = __shfl((int)dw[2 * c + 1][0], src2);
      const uint a3 = __shfl((int)dw[2 * c][1], src2);
      const uint b3 = __shfl((int)dw[2 * c + 1][1], src2);
      uint4v du = {useO ? b0 : a0, useO ? b1 : a1, useO ? b2 : a2, useO ? b3 : a3};
      const bf16x8 pa = __builtin_bit_cast(bf16x8, du);
      __builtin_amdgcn_s_setprio(1);
#pragma unroll
      for (int dj = 0; dj < 4; ++dj) {
        const bf16x8 bv = *(const bf16x8*)&Vts[vswz(dj * 16 + lr, 32 * c + lg * 8)];
        oacc[dj] = __builtin_amdgcn_mfma_f32_16x16x32_bf16(pa, bv, oacc[dj], 0, 0, 0);
      }
      __builtin_amdgcn_s_setprio(0);
    }

    // stage next tile (write kb+1 from regs, issue kb+2)
    if (kb < bx) {
      __syncthreads();
      write_k(); write_v();
      if (kb + 2 <= bx) { issue_k(kb + 2); issue_v(kb + 2); }
      __syncthreads();
    }
  }

  // ---- denominator: rowsum(q=lr) + phi_q.kk(q=lr), transpose via LDS ----
  float pkk = 0.f;
#pragma unroll
  for (int c = 0; c < 2; ++c)
#pragma unroll
    for (int i = 0; i < 8; ++i)
      pkk += (float)pq[c][i] * kks[32 * c + lg * 8 + i];
  pkk += __shfl_xor(pkk, 16);
  pkk += __shfl_xor(pkk, 32);
  float s = lsum;
  s += __shfl_xor(s, 16);
  s += __shfl_xor(s, 32);
  const float denom = s + pkk;            // valid for q = lr, all lanes
  if (l < 16) red[w][l] = denom;
  asm volatile("s_waitcnt lgkmcnt(0)" ::: "memory");
  __builtin_amdgcn_sched_barrier(0);

  // ---- epilogue: phi_q @ Z (MFMA), normalize, write ----
  f32x4 zacc[4] = {z4, z4, z4, z4};
  __builtin_amdgcn_s_setprio(1);
#pragma unroll
  for (int c = 0; c < 2; ++c) {
#pragma unroll
    for (int dj = 0; dj < 4; ++dj) {
      const bf16x8 bz = *(const bf16x8*)&Zts[vswz(dj * 16 + lr, 32 * c + lg * 8)];
      zacc[dj] = __builtin_amdgcn_mfma_f32_16x16x32_bf16(pq[c], bz, zacc[dj], 0, 0, 0);
    }
  }
  __builtin_amdgcn_s_setprio(0);

#pragma unroll
  for (int r = 0; r < 4; ++r) {
    const float rd = 1.f / red[w][lg * 4 + r];
    float* op = Og + (size_t)(q0 + w * 16 + lg * 4 + r) * ROWSTRIDE + headoff;
#pragma unroll
    for (int dj = 0; dj < 4; ++dj)
      op[dj * 16 + lr] = (oacc[dj][r] + zacc[dj][r]) * rd;
  }
}

extern "C" void kernel_launch(void* const* d_in, const int* in_sizes, int n_in,
                              void* d_out, int out_size, void* d_ws, size_t ws_size,
                              hipStream_t stream) {
  const float* Qg  = (const float*)d_in[0];
  const float* Kg  = (const float*)d_in[1];
  const float* Vg  = (const float*)d_in[2];
  const float* PKg  = (const float*)d_in[4];
  const float* PKVg = (const float*)d_in[5];
  float* Og = (float*)d_out;
  dim3 grid(NQT, BSZ * NHEAD);
  ntk_attn<<<grid, dim3(256), 0, stream>>>(Qg, Kg, Vg, PKg, PKVg, Og);
}